// Round 1
// baseline (490.793 us; speedup 1.0000x reference)
//
#include <hip/hip_runtime.h>
#include <math.h>

#define N_ROWS 400      // bs*Q
#define M_ROWS 80
#define K_CLS  134
#define PN     12544
#define PFULL  65536    // 256*256

__device__ __forceinline__ float wave_reduce_sum(float v) {
#pragma unroll
    for (int off = 32; off > 0; off >>= 1) v += __shfl_down(v, off, 64);
    return v;
}

// --- Kernel A: per-row softmax stats over (400,134) ---
__global__ void softmax_stats_kernel(const float* __restrict__ logits,
                                     float* __restrict__ rowmax,
                                     float* __restrict__ rowsum) {
    int n = blockIdx.x;
    const float* row = logits + n * K_CLS;
    int l = threadIdx.x;  // 64 threads = 1 wave
    float mx = -1e30f;
    for (int k = l; k < K_CLS; k += 64) mx = fmaxf(mx, row[k]);
#pragma unroll
    for (int off = 32; off > 0; off >>= 1) mx = fmaxf(mx, __shfl_down(mx, off, 64));
    mx = __shfl(mx, 0, 64);
    float se = 0.f;
    for (int k = l; k < K_CLS; k += 64) se += expf(row[k] - mx);
    se = wave_reduce_sum(se);
    if (l == 0) { rowmax[n] = mx; rowsum[n] = se; }
}

// --- Kernel B: gather y rows + row sums ---
__global__ void gather_y_kernel(const float* __restrict__ tgt_masks,
                                const int* __restrict__ point_idx,
                                float* __restrict__ Yw,
                                float* __restrict__ ysum) {
    int m = blockIdx.x;
    const float* row = tgt_masks + (size_t)m * PFULL;
    float acc = 0.f;
    for (int p = threadIdx.x; p < PN; p += blockDim.x) {
        float v = row[point_idx[p]];
        Yw[(size_t)m * PN + p] = v;
        acc += v;
    }
    __shared__ float sm[4];
    float w = wave_reduce_sum(acc);
    int lane = threadIdx.x & 63, wid = threadIdx.x >> 6;
    if (lane == 0) sm[wid] = w;
    __syncthreads();
    if (threadIdx.x == 0) ysum[m] = sm[0] + sm[1] + sm[2] + sm[3];
}

// --- Kernel C: gather x rows + softplus-sum + sigmoid-sum ---
__global__ void gather_x_kernel(const float* __restrict__ pred_masks,
                                const int* __restrict__ point_idx,
                                float* __restrict__ Xw,
                                float* __restrict__ spsum,
                                float* __restrict__ ssum) {
    int n = blockIdx.x;
    const float* row = pred_masks + (size_t)n * PFULL;
    float ssp = 0.f, sss = 0.f;
    for (int p = threadIdx.x; p < PN; p += blockDim.x) {
        float x = row[point_idx[p]];
        Xw[(size_t)n * PN + p] = x;
        float sp = fmaxf(x, 0.f) + log1pf(expf(-fabsf(x)));  // stable softplus
        float s  = 1.f / (1.f + expf(-x));
        ssp += sp; sss += s;
    }
    __shared__ float sm1[4], sm2[4];
    float w1 = wave_reduce_sum(ssp);
    float w2 = wave_reduce_sum(sss);
    int lane = threadIdx.x & 63, wid = threadIdx.x >> 6;
    if (lane == 0) { sm1[wid] = w1; sm2[wid] = w2; }
    __syncthreads();
    if (threadIdx.x == 0) {
        spsum[n] = sm1[0] + sm1[1] + sm1[2] + sm1[3];
        ssum[n]  = sm2[0] + sm2[1] + sm2[2] + sm2[3];
    }
}

// --- Kernel D: tiled fp32 matmul, xy and sy accumulators, K-split + atomics ---
#define BT 32
#define TK 32
#define KSPLIT 8
#define KCHUNK (PN / KSPLIT)   // 1568, divisible by TK (49 iters)

__global__ __launch_bounds__(256) void matmul_kernel(const float* __restrict__ Xw,
                                                     const float* __restrict__ Yw,
                                                     float* __restrict__ xyacc,
                                                     float* __restrict__ syacc) {
    __shared__ float Xs[TK][BT + 1];
    __shared__ float Ss[TK][BT + 1];
    __shared__ float Ys[TK][BT + 1];
    int n0 = blockIdx.x * BT;
    int m0 = blockIdx.y * BT;
    int kbase = blockIdx.z * KCHUNK;
    int t = threadIdx.x;
    int tx = t & 15, ty = t >> 4;

    float axy[2][2] = {{0.f,0.f},{0.f,0.f}};
    float asy[2][2] = {{0.f,0.f},{0.f,0.f}};

    for (int kt = 0; kt < KCHUNK; kt += TK) {
        int k0 = kbase + kt;
#pragma unroll
        for (int i = t; i < BT * TK; i += 256) {
            int nl = i >> 5, kl = i & 31;
            int n = n0 + nl;
            float xv = (n < N_ROWS) ? Xw[(size_t)n * PN + k0 + kl] : 0.f;
            Xs[kl][nl] = xv;
            Ss[kl][nl] = 1.f / (1.f + expf(-xv));
            int m = m0 + nl;
            Ys[kl][nl] = (m < M_ROWS) ? Yw[(size_t)m * PN + k0 + kl] : 0.f;
        }
        __syncthreads();
#pragma unroll 8
        for (int k = 0; k < TK; ++k) {
            float x0 = Xs[k][2*ty], x1 = Xs[k][2*ty+1];
            float s0 = Ss[k][2*ty], s1 = Ss[k][2*ty+1];
            float y0 = Ys[k][2*tx], y1 = Ys[k][2*tx+1];
            axy[0][0] += x0*y0; axy[0][1] += x0*y1;
            axy[1][0] += x1*y0; axy[1][1] += x1*y1;
            asy[0][0] += s0*y0; asy[0][1] += s0*y1;
            asy[1][0] += s1*y0; asy[1][1] += s1*y1;
        }
        __syncthreads();
    }
#pragma unroll
    for (int i = 0; i < 2; ++i)
#pragma unroll
        for (int j = 0; j < 2; ++j) {
            int n = n0 + 2*ty + i, m = m0 + 2*tx + j;
            if (n < N_ROWS && m < M_ROWS) {
                atomicAdd(&xyacc[n * M_ROWS + m], axy[i][j]);
                atomicAdd(&syacc[n * M_ROWS + m], asy[i][j]);
            }
        }
}

// --- Kernel E: combine all cost terms ---
__global__ void combine_kernel(const float* __restrict__ logits,
                               const int* __restrict__ tgt_labels,
                               const float* __restrict__ rowmax,
                               const float* __restrict__ rowsum,
                               const float* __restrict__ spsum,
                               const float* __restrict__ ssum,
                               const float* __restrict__ ysum,
                               const float* __restrict__ xyacc,
                               const float* __restrict__ syacc,
                               float* __restrict__ out) {
    int idx = blockIdx.x * blockDim.x + threadIdx.x;
    if (idx >= N_ROWS * M_ROWS) return;
    int n = idx / M_ROWS, m = idx % M_ROWS;
    int tid = tgt_labels[m];
    tid = min(max(tid, 0), K_CLS - 1);
    float p = expf(logits[n * K_CLS + tid] - rowmax[n]) / rowsum[n];
    float cost_class = -p;
    float cost_mask = (spsum[n] - xyacc[idx]) * (1.0f / PN);
    float cost_dice = 1.f - (2.f * syacc[idx] + 1.f) / (ssum[n] + ysum[m] + 1.f);
    out[idx] = 2.f * cost_class + 5.f * cost_mask + 5.f * cost_dice;
}

extern "C" void kernel_launch(void* const* d_in, const int* in_sizes, int n_in,
                              void* d_out, int out_size, void* d_ws, size_t ws_size,
                              hipStream_t stream) {
    const float* pred_logits = (const float*)d_in[0];   // (4,100,134)
    const float* pred_masks  = (const float*)d_in[1];   // (4,100,256,256)
    const int*   tgt_labels  = (const int*)d_in[2];     // (80,)
    const float* tgt_masks   = (const float*)d_in[3];   // (80,256,256)
    const int*   point_idx   = (const int*)d_in[4];     // (12544,)
    float* out = (float*)d_out;                         // (4,100,80)

    // workspace carve-up (floats)
    char* ws = (char*)d_ws;
    size_t off = 0;
    auto carve = [&](size_t nfloats) {
        float* p = (float*)(ws + off);
        off += ((nfloats * 4 + 255) / 256) * 256;
        return p;
    };
    float* Xw     = carve((size_t)N_ROWS * PN);   // 20.07 MB
    float* Yw     = carve((size_t)M_ROWS * PN);   //  4.01 MB
    float* spsum  = carve(N_ROWS);
    float* ssum   = carve(N_ROWS);
    float* ysum   = carve(M_ROWS);
    float* rowmax = carve(N_ROWS);
    float* rowsum = carve(N_ROWS);
    float* xyacc  = carve(N_ROWS * M_ROWS);
    float* syacc  = carve(N_ROWS * M_ROWS);
    (void)ws_size;

    softmax_stats_kernel<<<N_ROWS, 64, 0, stream>>>(pred_logits, rowmax, rowsum);
    gather_y_kernel<<<M_ROWS, 256, 0, stream>>>(tgt_masks, point_idx, Yw, ysum);
    gather_x_kernel<<<N_ROWS, 256, 0, stream>>>(pred_masks, point_idx, Xw, spsum, ssum);

    // zero the K-split accumulators (xyacc and syacc are contiguous)
    hipMemsetAsync(xyacc, 0, 2 * ((size_t)N_ROWS * M_ROWS * 4 + 0) + 256, stream);

    dim3 grid((N_ROWS + BT - 1) / BT, (M_ROWS + BT - 1) / BT, KSPLIT);
    matmul_kernel<<<grid, 256, 0, stream>>>(Xw, Yw, xyacc, syacc);

    combine_kernel<<<(N_ROWS * M_ROWS + 255) / 256, 256, 0, stream>>>(
        pred_logits, tgt_labels, rowmax, rowsum, spsum, ssum, ysum, xyacc, syacc, out);
}

// Round 2
// 247.327 us; speedup vs baseline: 1.9844x; 1.9844x over previous
//
#include <hip/hip_runtime.h>
#include <math.h>

#define N_ROWS 400      // bs*Q
#define M_ROWS 80
#define MPAD   96       // padded M: col 80 = wgt (gives ssum/spsum), 81-95 = 0
#define K_CLS  134
#define PN     12544
#define PFULL  65536    // 256*256
#define NSUB   25       // 400/16 n-subtiles
#define TSTEPS 2048     // PFULL/32 MFMA k-steps
#define KSPLIT 64
#define TPB    (TSTEPS / KSPLIT)   // 32 k-steps per block

typedef __attribute__((ext_vector_type(4))) float  f32x4;
typedef __attribute__((ext_vector_type(8))) __bf16 bf16x8;

__device__ __forceinline__ float wave_reduce_sum(float v) {
#pragma unroll
    for (int off = 32; off > 0; off >>= 1) v += __shfl_down(v, off, 64);
    return v;
}

// --- softmax stats over (400,134) ---
__global__ void softmax_stats_kernel(const float* __restrict__ logits,
                                     float* __restrict__ rowmax,
                                     float* __restrict__ rowsum) {
    int n = blockIdx.x;
    const float* row = logits + n * K_CLS;
    int l = threadIdx.x;  // 64 threads = 1 wave
    float mx = -1e30f;
    for (int k = l; k < K_CLS; k += 64) mx = fmaxf(mx, row[k]);
#pragma unroll
    for (int off = 32; off > 0; off >>= 1) mx = fmaxf(mx, __shfl_down(mx, off, 64));
    mx = __shfl(mx, 0, 64);
    float se = 0.f;
    for (int k = l; k < K_CLS; k += 64) se += expf(row[k] - mx);
    se = wave_reduce_sum(se);
    if (l == 0) { rowmax[n] = mx; rowsum[n] = se; }
}

// --- scatter binary weights ---
__global__ void scatter_wgt_kernel(const int* __restrict__ point_idx,
                                   float* __restrict__ wgt) {
    int i = blockIdx.x * blockDim.x + threadIdx.x;
    if (i < PN) wgt[point_idx[i]] = 1.0f;
}

// --- build Yb in MFMA-B-fragment order: frag (t,j), lane l holds
//     B[k = t*32 + (l>>4)*8 + jj][mcol = 16*j + (l&15)] = wgt[k]*y[m][k]
//     col 80 = wgt[k]; cols 81..95 = 0.  Also accumulates ysum[m]. ---
__global__ __launch_bounds__(256) void yformat_kernel(
        const float* __restrict__ tgt_masks, const float* __restrict__ wgt,
        __bf16* __restrict__ Yb, float* __restrict__ ysum) {
    int j = blockIdx.x >> 4;          // m-subtile 0..5
    int tchunk = blockIdx.x & 15;     // 0..15, 128 t's each
    int tloc = threadIdx.x >> 6;      // 0..3
    int lane = threadIdx.x & 63;
    int colL = lane & 15, quad = lane >> 4;
    int m = 16 * j + colL;
    const float* yrow = tgt_masks + (size_t)m * PFULL;  // only deref'd if m<80
    bf16x8* out = (bf16x8*)Yb;
    float part = 0.f;
    for (int t = tchunk * 128 + tloc; t < tchunk * 128 + 128; t += 4) {
        int k = t * 32 + quad * 8;
        f32x4 w0 = *(const f32x4*)(wgt + k);
        f32x4 w1 = *(const f32x4*)(wgt + k + 4);
        bf16x8 v;
        if (m < M_ROWS) {
            f32x4 y0 = *(const f32x4*)(yrow + k);
            f32x4 y1 = *(const f32x4*)(yrow + k + 4);
#pragma unroll
            for (int jj = 0; jj < 4; ++jj) {
                float v0 = w0[jj] * y0[jj], v1 = w1[jj] * y1[jj];
                part += v0 + v1;
                v[jj] = (__bf16)v0; v[jj + 4] = (__bf16)v1;
            }
        } else if (m == M_ROWS) {
#pragma unroll
            for (int jj = 0; jj < 4; ++jj) { v[jj] = (__bf16)w0[jj]; v[jj + 4] = (__bf16)w1[jj]; }
        } else {
#pragma unroll
            for (int jj = 0; jj < 8; ++jj) v[jj] = (__bf16)0.f;
        }
        out[(size_t)(t * 6 + j) * 64 + lane] = v;
    }
    if (m < M_ROWS) atomicAdd(&ysum[m], part);
}

// --- fused MFMA kernel: per wave one 16-row n-tile, all MPAD columns.
//     LDS-free: A built in registers from coalesced pred_masks reads,
//     B-frags are coalesced 1024B loads from pre-formatted Yb. ---
__global__ __launch_bounds__(256) void mfma_kernel(
        const float* __restrict__ pred_masks,
        const __bf16* __restrict__ Yb,
        float* __restrict__ xyacc, float* __restrict__ syacc,
        float* __restrict__ ssum, float* __restrict__ spsum) {
    int wave = threadIdx.x >> 6;
    int lane = threadIdx.x & 63;
    int nsub = blockIdx.x * 4 + wave;
    int nclamp = nsub < NSUB ? nsub : NSUB - 1;   // clamped rows recompute, skip epilogue
    int n0 = nclamp * 16;
    int colL = lane & 15;
    int quad = lane >> 4;
    int tbase = blockIdx.y * TPB;

    const float* arow = pred_masks + (size_t)(n0 + colL) * PFULL;  // A[m=lane&15]
    const bf16x8* Yfrag = (const bf16x8*)Yb;

    f32x4 accX[5], accS[6], accSP;
    f32x4 zero = {0.f, 0.f, 0.f, 0.f};
#pragma unroll
    for (int j = 0; j < 5; ++j) accX[j] = zero;
#pragma unroll
    for (int j = 0; j < 6; ++j) accS[j] = zero;
    accSP = zero;

    auto load = [&](int i, f32x4& A0, f32x4& A1, bf16x8* B) {
        int t = tbase + i;
        const f32x4* p = (const f32x4*)(arow + (size_t)t * 32 + quad * 8);
        A0 = p[0]; A1 = p[1];
        const bf16x8* q = Yfrag + (size_t)(t * 6) * 64 + lane;
#pragma unroll
        for (int j = 0; j < 6; ++j) B[j] = q[(size_t)j * 64];
    };

    auto compute = [&](f32x4 A0, f32x4 A1, const bf16x8* B) {
        bf16x8 aX, aS, aSP;
#pragma unroll
        for (int jj = 0; jj < 8; ++jj) {
            float x  = (jj < 4) ? A0[jj & 3] : A1[jj & 3];
            float ax = fabsf(x);
            float e  = __expf(-ax);
            float inv = __builtin_amdgcn_rcpf(1.0f + e);
            float sig = (x >= 0.f) ? inv : e * inv;
            float sp  = fmaxf(x, 0.f) + __logf(1.0f + e);
            aX[jj] = (__bf16)x; aS[jj] = (__bf16)sig; aSP[jj] = (__bf16)sp;
        }
#pragma unroll
        for (int j = 0; j < 5; ++j)
            accX[j] = __builtin_amdgcn_mfma_f32_16x16x32_bf16(aX, B[j], accX[j], 0, 0, 0);
#pragma unroll
        for (int j = 0; j < 6; ++j)
            accS[j] = __builtin_amdgcn_mfma_f32_16x16x32_bf16(aS, B[j], accS[j], 0, 0, 0);
        accSP = __builtin_amdgcn_mfma_f32_16x16x32_bf16(aSP, B[5], accSP, 0, 0, 0);
    };

    f32x4 A0a, A1a, A0b, A1b;
    bf16x8 Ba[6], Bb[6];
    load(0, A0a, A1a, Ba);
    for (int i = 0; i < TPB; i += 2) {     // ping-pong: loads prefetch next step
        load(i + 1, A0b, A1b, Bb);
        compute(A0a, A1a, Ba);
        if (i + 2 < TPB) load(i + 2, A0a, A1a, Ba);
        compute(A0b, A1b, Bb);
    }

    if (nsub < NSUB) {
        // C/D: n = n0 + quad*4 + reg, m = 16*j + colL  [verified m89/m91 layout]
#pragma unroll
        for (int j = 0; j < 5; ++j)
#pragma unroll
            for (int r = 0; r < 4; ++r) {
                int n = n0 + quad * 4 + r;
                int m = 16 * j + colL;
                atomicAdd(&xyacc[n * M_ROWS + m], accX[j][r]);
                atomicAdd(&syacc[n * M_ROWS + m], accS[j][r]);
            }
        if (colL == 0) {   // column 80 of padded Y = wgt → row sums
#pragma unroll
            for (int r = 0; r < 4; ++r) {
                int n = n0 + quad * 4 + r;
                atomicAdd(&ssum[n], accS[5][r]);
                atomicAdd(&spsum[n], accSP[r]);
            }
        }
    }
}

// --- combine all cost terms ---
__global__ void combine_kernel(const float* __restrict__ logits,
                               const int* __restrict__ tgt_labels,
                               const float* __restrict__ rowmax,
                               const float* __restrict__ rowsum,
                               const float* __restrict__ spsum,
                               const float* __restrict__ ssum,
                               const float* __restrict__ ysum,
                               const float* __restrict__ xyacc,
                               const float* __restrict__ syacc,
                               float* __restrict__ out) {
    int idx = blockIdx.x * blockDim.x + threadIdx.x;
    if (idx >= N_ROWS * M_ROWS) return;
    int n = idx / M_ROWS, m = idx % M_ROWS;
    int tid = tgt_labels[m];
    tid = min(max(tid, 0), K_CLS - 1);
    float p = expf(logits[n * K_CLS + tid] - rowmax[n]) / rowsum[n];
    float cost_class = -p;
    float cost_mask = (spsum[n] - xyacc[idx]) * (1.0f / PN);
    float cost_dice = 1.f - (2.f * syacc[idx] + 1.f) / (ssum[n] + ysum[m] + 1.f);
    out[idx] = 2.f * cost_class + 5.f * cost_mask + 5.f * cost_dice;
}

extern "C" void kernel_launch(void* const* d_in, const int* in_sizes, int n_in,
                              void* d_out, int out_size, void* d_ws, size_t ws_size,
                              hipStream_t stream) {
    const float* pred_logits = (const float*)d_in[0];   // (4,100,134)
    const float* pred_masks  = (const float*)d_in[1];   // (4,100,256,256)
    const int*   tgt_labels  = (const int*)d_in[2];     // (80,)
    const float* tgt_masks   = (const float*)d_in[3];   // (80,256,256)
    const int*   point_idx   = (const int*)d_in[4];     // (12544,)
    float* out = (float*)d_out;                         // (4,100,80)

    char* ws = (char*)d_ws;
    size_t off = 0;
    auto carve = [&](size_t nfloats) {
        float* p = (float*)(ws + off);
        off += ((nfloats * 4 + 255) / 256) * 256;
        return p;
    };
    // ---- zero-init region (one memset) ----
    float* xyacc  = carve((size_t)N_ROWS * M_ROWS);
    float* syacc  = carve((size_t)N_ROWS * M_ROWS);
    float* spsum  = carve(N_ROWS);
    float* ssum   = carve(N_ROWS);
    float* ysum   = carve(M_ROWS);
    float* wgt    = carve(PFULL);
    size_t zero_bytes = off;
    // ---- no-init region ----
    float* rowmax = carve(N_ROWS);
    float* rowsum = carve(N_ROWS);
    __bf16* Yb = (__bf16*)(ws + off);                   // 2048*6*1024 B = 12.6 MB
    off += (size_t)TSTEPS * 6 * 1024;
    (void)ws_size;

    hipMemsetAsync(xyacc, 0, zero_bytes, stream);
    scatter_wgt_kernel<<<(PN + 255) / 256, 256, 0, stream>>>(point_idx, wgt);
    softmax_stats_kernel<<<N_ROWS, 64, 0, stream>>>(pred_logits, rowmax, rowsum);
    yformat_kernel<<<96, 256, 0, stream>>>(tgt_masks, wgt, Yb, ysum);
    dim3 grid((NSUB + 3) / 4, KSPLIT);   // 7 x 64 blocks, 4 waves/block
    mfma_kernel<<<grid, 256, 0, stream>>>(pred_masks, Yb, xyacc, syacc, ssum, spsum);
    combine_kernel<<<(N_ROWS * M_ROWS + 255) / 256, 256, 0, stream>>>(
        pred_logits, tgt_labels, rowmax, rowsum, spsum, ssum, ysum, xyacc, syacc, out);
}

// Round 3
// 225.452 us; speedup vs baseline: 2.1769x; 1.0970x over previous
//
#include <hip/hip_runtime.h>
#include <math.h>

#define N_ROWS 400      // bs*Q
#define M_ROWS 80
#define MPAD   96       // padded M: col 80 = wgt (gives ssum/spsum), 81-95 = 0
#define K_CLS  134
#define PN     12544
#define PFULL  65536    // 256*256
#define NSUB   25       // 400/16 n-subtiles
#define TSTEPS 2048     // PFULL/32 MFMA k-steps
#define KSPLIT 128
#define TPB    (TSTEPS / KSPLIT)   // 16 k-steps per block

typedef __attribute__((ext_vector_type(4))) float  f32x4;
typedef __attribute__((ext_vector_type(8))) __bf16 bf16x8;

__device__ __forceinline__ float wave_reduce_sum(float v) {
#pragma unroll
    for (int off = 32; off > 0; off >>= 1) v += __shfl_down(v, off, 64);
    return v;
}

// --- softmax stats over (400,134) ---
__global__ void softmax_stats_kernel(const float* __restrict__ logits,
                                     float* __restrict__ rowmax,
                                     float* __restrict__ rowsum) {
    int n = blockIdx.x;
    const float* row = logits + n * K_CLS;
    int l = threadIdx.x;  // 64 threads = 1 wave
    float mx = -1e30f;
    for (int k = l; k < K_CLS; k += 64) mx = fmaxf(mx, row[k]);
#pragma unroll
    for (int off = 32; off > 0; off >>= 1) mx = fmaxf(mx, __shfl_down(mx, off, 64));
    mx = __shfl(mx, 0, 64);
    float se = 0.f;
    for (int k = l; k < K_CLS; k += 64) se += expf(row[k] - mx);
    se = wave_reduce_sum(se);
    if (l == 0) { rowmax[n] = mx; rowsum[n] = se; }
}

// --- scatter binary weights ---
__global__ void scatter_wgt_kernel(const int* __restrict__ point_idx,
                                   float* __restrict__ wgt) {
    int i = blockIdx.x * blockDim.x + threadIdx.x;
    if (i < PN) wgt[point_idx[i]] = 1.0f;
}

// --- build Yb in MFMA-B-fragment order: frag (t,j), lane l holds
//     B[k = t*32 + (l>>4)*8 + jj][mcol = 16*j + (l&15)] = wgt[k]*y[m][k]
//     col 80 = wgt[k]; cols 81..95 = 0.  Also accumulates ysum[m].
//     Grid: 384 blocks = 6 j-subtiles x 64 t-chunks (32 t's each). ---
__global__ __launch_bounds__(256) void yformat_kernel(
        const float* __restrict__ tgt_masks, const float* __restrict__ wgt,
        __bf16* __restrict__ Yb, float* __restrict__ ysum) {
    int j = blockIdx.x >> 6;          // m-subtile 0..5
    int tchunk = blockIdx.x & 63;     // 0..63, 32 t's each
    int tloc = threadIdx.x >> 6;      // 0..3
    int lane = threadIdx.x & 63;
    int colL = lane & 15, quad = lane >> 4;
    int m = 16 * j + colL;
    const float* yrow = tgt_masks + (size_t)m * PFULL;  // only deref'd if m<80
    bf16x8* out = (bf16x8*)Yb;
    float part = 0.f;
    int tbase = tchunk * 32;
    for (int t = tbase + tloc; t < tbase + 32; t += 4) {
        int k = t * 32 + quad * 8;
        f32x4 w0 = *(const f32x4*)(wgt + k);
        f32x4 w1 = *(const f32x4*)(wgt + k + 4);
        bf16x8 v;
        if (m < M_ROWS) {
            f32x4 y0 = *(const f32x4*)(yrow + k);
            f32x4 y1 = *(const f32x4*)(yrow + k + 4);
#pragma unroll
            for (int jj = 0; jj < 4; ++jj) {
                float v0 = w0[jj] * y0[jj], v1 = w1[jj] * y1[jj];
                part += v0 + v1;
                v[jj] = (__bf16)v0; v[jj + 4] = (__bf16)v1;
            }
        } else if (m == M_ROWS) {
#pragma unroll
            for (int jj = 0; jj < 4; ++jj) { v[jj] = (__bf16)w0[jj]; v[jj + 4] = (__bf16)w1[jj]; }
        } else {
#pragma unroll
            for (int jj = 0; jj < 8; ++jj) v[jj] = (__bf16)0.f;
        }
        out[(size_t)(t * 6 + j) * 64 + lane] = v;
    }
    // reduce the 4 quads holding the same m before the atomic
    part += __shfl_down(part, 32, 64);
    part += __shfl_down(part, 16, 64);
    if (quad == 0 && m < M_ROWS) atomicAdd(&ysum[m], part);
}

// --- fused MFMA kernel: per wave one 16-row n-tile, all MPAD columns.
//     LDS-free: A built in registers from coalesced pred_masks reads,
//     B-frags are coalesced 1024B loads from pre-formatted Yb. ---
__global__ __launch_bounds__(256) void mfma_kernel(
        const float* __restrict__ pred_masks,
        const __bf16* __restrict__ Yb,
        float* __restrict__ xyacc, float* __restrict__ syacc,
        float* __restrict__ ssum, float* __restrict__ spsum) {
    int wave = threadIdx.x >> 6;
    int lane = threadIdx.x & 63;
    int nsub = blockIdx.x * 4 + wave;
    int nclamp = nsub < NSUB ? nsub : NSUB - 1;   // clamped rows recompute, skip epilogue
    int n0 = nclamp * 16;
    int colL = lane & 15;
    int quad = lane >> 4;
    int tbase = blockIdx.y * TPB;

    const float* arow = pred_masks + (size_t)(n0 + colL) * PFULL;  // A[m=lane&15]
    const bf16x8* Yfrag = (const bf16x8*)Yb;

    f32x4 accX[5], accS[6], accSP;
    f32x4 zero = {0.f, 0.f, 0.f, 0.f};
#pragma unroll
    for (int j = 0; j < 5; ++j) accX[j] = zero;
#pragma unroll
    for (int j = 0; j < 6; ++j) accS[j] = zero;
    accSP = zero;

    auto load = [&](int i, f32x4& A0, f32x4& A1, bf16x8* B) {
        int t = tbase + i;
        const f32x4* p = (const f32x4*)(arow + (size_t)t * 32 + quad * 8);
        A0 = p[0]; A1 = p[1];
        const bf16x8* q = Yfrag + (size_t)(t * 6) * 64 + lane;
#pragma unroll
        for (int j = 0; j < 6; ++j) B[j] = q[(size_t)j * 64];
    };

    auto compute = [&](f32x4 A0, f32x4 A1, const bf16x8* B) {
        bf16x8 aX, aS, aSP;
#pragma unroll
        for (int jj = 0; jj < 8; ++jj) {
            float x  = (jj < 4) ? A0[jj & 3] : A1[jj & 3];
            float ax = fabsf(x);
            float e  = __expf(-ax);
            float inv = __builtin_amdgcn_rcpf(1.0f + e);
            float sig = (x >= 0.f) ? inv : e * inv;
            float sp  = fmaxf(x, 0.f) + __logf(1.0f + e);
            aX[jj] = (__bf16)x; aS[jj] = (__bf16)sig; aSP[jj] = (__bf16)sp;
        }
#pragma unroll
        for (int j = 0; j < 5; ++j)
            accX[j] = __builtin_amdgcn_mfma_f32_16x16x32_bf16(aX, B[j], accX[j], 0, 0, 0);
#pragma unroll
        for (int j = 0; j < 6; ++j)
            accS[j] = __builtin_amdgcn_mfma_f32_16x16x32_bf16(aS, B[j], accS[j], 0, 0, 0);
        accSP = __builtin_amdgcn_mfma_f32_16x16x32_bf16(aSP, B[5], accSP, 0, 0, 0);
    };

    f32x4 A0a, A1a, A0b, A1b;
    bf16x8 Ba[6], Bb[6];
    load(0, A0a, A1a, Ba);
    for (int i = 0; i < TPB; i += 2) {     // ping-pong: loads prefetch next step
        load(i + 1, A0b, A1b, Bb);
        compute(A0a, A1a, Ba);
        if (i + 2 < TPB) load(i + 2, A0a, A1a, Ba);
        compute(A0b, A1b, Bb);
    }

    if (nsub < NSUB) {
        // C/D: n = n0 + quad*4 + reg, m = 16*j + colL  [verified m89/m91 layout]
#pragma unroll
        for (int j = 0; j < 5; ++j)
#pragma unroll
            for (int r = 0; r < 4; ++r) {
                int n = n0 + quad * 4 + r;
                int m = 16 * j + colL;
                atomicAdd(&xyacc[n * M_ROWS + m], accX[j][r]);
                atomicAdd(&syacc[n * M_ROWS + m], accS[j][r]);
            }
        if (colL == 0) {   // column 80 of padded Y = wgt → row sums
#pragma unroll
            for (int r = 0; r < 4; ++r) {
                int n = n0 + quad * 4 + r;
                atomicAdd(&ssum[n], accS[5][r]);
                atomicAdd(&spsum[n], accSP[r]);
            }
        }
    }
}

// --- combine all cost terms ---
__global__ void combine_kernel(const float* __restrict__ logits,
                               const int* __restrict__ tgt_labels,
                               const float* __restrict__ rowmax,
                               const float* __restrict__ rowsum,
                               const float* __restrict__ spsum,
                               const float* __restrict__ ssum,
                               const float* __restrict__ ysum,
                               const float* __restrict__ xyacc,
                               const float* __restrict__ syacc,
                               float* __restrict__ out) {
    int idx = blockIdx.x * blockDim.x + threadIdx.x;
    if (idx >= N_ROWS * M_ROWS) return;
    int n = idx / M_ROWS, m = idx % M_ROWS;
    int tid = tgt_labels[m];
    tid = min(max(tid, 0), K_CLS - 1);
    float p = expf(logits[n * K_CLS + tid] - rowmax[n]) / rowsum[n];
    float cost_class = -p;
    float cost_mask = (spsum[n] - xyacc[idx]) * (1.0f / PN);
    float cost_dice = 1.f - (2.f * syacc[idx] + 1.f) / (ssum[n] + ysum[m] + 1.f);
    out[idx] = 2.f * cost_class + 5.f * cost_mask + 5.f * cost_dice;
}

extern "C" void kernel_launch(void* const* d_in, const int* in_sizes, int n_in,
                              void* d_out, int out_size, void* d_ws, size_t ws_size,
                              hipStream_t stream) {
    const float* pred_logits = (const float*)d_in[0];   // (4,100,134)
    const float* pred_masks  = (const float*)d_in[1];   // (4,100,256,256)
    const int*   tgt_labels  = (const int*)d_in[2];     // (80,)
    const float* tgt_masks   = (const float*)d_in[3];   // (80,256,256)
    const int*   point_idx   = (const int*)d_in[4];     // (12544,)
    float* out = (float*)d_out;                         // (4,100,80)

    char* ws = (char*)d_ws;
    size_t off = 0;
    auto carve = [&](size_t nfloats) {
        float* p = (float*)(ws + off);
        off += ((nfloats * 4 + 255) / 256) * 256;
        return p;
    };
    // ---- zero-init region (one memset) ----
    float* xyacc  = carve((size_t)N_ROWS * M_ROWS);
    float* syacc  = carve((size_t)N_ROWS * M_ROWS);
    float* spsum  = carve(N_ROWS);
    float* ssum   = carve(N_ROWS);
    float* ysum   = carve(M_ROWS);
    float* wgt    = carve(PFULL);
    size_t zero_bytes = off;
    // ---- no-init region ----
    float* rowmax = carve(N_ROWS);
    float* rowsum = carve(N_ROWS);
    __bf16* Yb = (__bf16*)(ws + off);                   // 2048*6*1024 B = 12.6 MB
    off += (size_t)TSTEPS * 6 * 1024;
    (void)ws_size;

    hipMemsetAsync(xyacc, 0, zero_bytes, stream);
    scatter_wgt_kernel<<<(PN + 255) / 256, 256, 0, stream>>>(point_idx, wgt);
    yformat_kernel<<<384, 256, 0, stream>>>(tgt_masks, wgt, Yb, ysum);
    dim3 grid((NSUB + 3) / 4, KSPLIT);   // 7 x 128 blocks, 4 waves/block
    mfma_kernel<<<grid, 256, 0, stream>>>(pred_masks, Yb, xyacc, syacc, ssum, spsum);
    softmax_stats_kernel<<<N_ROWS, 64, 0, stream>>>(pred_logits, rowmax, rowsum);
    combine_kernel<<<(N_ROWS * M_ROWS + 255) / 256, 256, 0, stream>>>(
        pred_logits, tgt_labels, rowmax, rowsum, spsum, ssum, ysum, xyacc, syacc, out);
}